// Round 1
// baseline (520.517 us; speedup 1.0000x reference)
//
#include <hip/hip_runtime.h>
#include <stdint.h>

#define TEMPERATURE 0.07f
#define MARGIN 0.1f
#define D_DIM 512
#define BM 128
#define BN 128
#define BK 64

typedef __bf16 bf16x8 __attribute__((ext_vector_type(8)));
typedef float f32x4 __attribute__((ext_vector_type(4)));

__device__ __forceinline__ unsigned short f2bf(float f) {
    unsigned int u = __float_as_uint(f);
    unsigned int r = (u + 0x7fffu + ((u >> 16) & 1u)) >> 16;  // RNE
    return (unsigned short)r;
}

// Direct global->LDS async copy, 16B per lane. LDS dest is wave-uniform base,
// HW adds lane*16. AS casts done via integer round-trip (low 32 bits of a
// generic LDS pointer == AS3 offset on gfx9+).
__device__ __forceinline__ void async_load16(const void* gptr, const void* lptr) {
    __builtin_amdgcn_global_load_lds(
        (const __attribute__((address_space(1))) uint32_t*)(uintptr_t)gptr,
        (__attribute__((address_space(3))) uint32_t*)(uint32_t)(uintptr_t)lptr,
        16, 0, 0);
}

// One wave per row: L2-normalize 512 fp32 -> bf16 bits.
__global__ __launch_bounds__(64) void normalize_rows_kernel(
    const float* __restrict__ in, unsigned short* __restrict__ out) {
    const int row = blockIdx.x;
    const int lane = threadIdx.x;
    const float4* in4 = (const float4*)(in + (size_t)row * D_DIM);
    float4 a = in4[lane];
    float4 b = in4[lane + 64];
    float ss = a.x * a.x + a.y * a.y + a.z * a.z + a.w * a.w +
               b.x * b.x + b.y * b.y + b.z * b.z + b.w * b.w;
#pragma unroll
    for (int off = 32; off > 0; off >>= 1) ss += __shfl_down(ss, off);
    ss = __shfl(ss, 0);
    const float inv = 1.0f / fmaxf(sqrtf(ss), 1e-12f);
    ushort4 oa, ob;
    oa.x = f2bf(a.x * inv); oa.y = f2bf(a.y * inv);
    oa.z = f2bf(a.z * inv); oa.w = f2bf(a.w * inv);
    ob.x = f2bf(b.x * inv); ob.y = f2bf(b.y * inv);
    ob.z = f2bf(b.z * inv); ob.w = f2bf(b.w * inv);
    ushort4* o4 = (ushort4*)(out + (size_t)row * D_DIM);
    o4[lane] = oa;
    o4[lane + 64] = ob;
}

// 128x128 tile of logits per block; fused log-sigmoid loss epilogue.
// S, T are row-major [N, 512] bf16 (normalized). C = S * T^T.
__global__ __launch_bounds__(256) void gemm_loss_kernel(
    const unsigned short* __restrict__ S, const unsigned short* __restrict__ T,
    float* __restrict__ partial, int N) {
    __shared__ __align__(16) unsigned short As[BM * BK];  // 16 KB
    __shared__ __align__(16) unsigned short Bs[BN * BK];  // 16 KB
    __shared__ float wsums[4];

    const int tid = threadIdx.x;
    const int wave = tid >> 6;
    const int lane = tid & 63;
    const int wm = wave >> 1;      // wave row (0..1), 64 rows each
    const int wn = wave & 1;       // wave col (0..1), 64 cols each
    const int quad = lane >> 4;    // 0..3
    const int m16 = lane & 15;     // 0..15
    const size_t rowBase = (size_t)blockIdx.y * BM;
    const size_t colBase = (size_t)blockIdx.x * BN;

    f32x4 acc[4][4];
#pragma unroll
    for (int i = 0; i < 4; ++i)
#pragma unroll
        for (int j = 0; j < 4; ++j) acc[i][j] = (f32x4){0.f, 0.f, 0.f, 0.f};

    // Staging geometry: chunk c (0..15) = 1 KB = rows [8c, 8c+8) of the
    // 128x64 tile. Lane i of the owning wave writes LDS base+16i, i.e.
    // row 8c + i/8, k-chunk position i%8. We fetch global k-chunk
    // (i%8)^(row%8) so reads can XOR-unswizzle -> conflict-free ds_read_b128.
    const int sub = lane >> 3;                 // row within chunk, 0..7
    const int kch = (lane & 7) ^ sub;          // global k-chunk to fetch
    const unsigned short* Sg = S + rowBase * D_DIM;
    const unsigned short* Tg = T + colBase * D_DIM;

    for (int k0 = 0; k0 < D_DIM; k0 += BK) {
        __syncthreads();  // LDS from previous iter fully consumed
#pragma unroll
        for (int r = 0; r < 4; ++r) {
            const int c = wave * 4 + r;
            const int rowA = c * 8 + sub;
            const size_t goff = (size_t)rowA * D_DIM + k0 + kch * 8;
            async_load16(Sg + goff, (const char*)As + c * 1024);
            async_load16(Tg + goff, (const char*)Bs + c * 1024);
        }
        __syncthreads();  // drains vmcnt(0): staging complete
#pragma unroll
        for (int kk = 0; kk < 2; ++kk) {
            bf16x8 af[4], bfr[4];
#pragma unroll
            for (int mt = 0; mt < 4; ++mt) {
                const int m = wm * 64 + mt * 16 + m16;
                const int pos = (kk * 4 + quad) ^ (m & 7);
                af[mt] = *(const bf16x8*)((const char*)As + m * 128 + pos * 16);
            }
#pragma unroll
            for (int nt = 0; nt < 4; ++nt) {
                const int n = wn * 64 + nt * 16 + m16;
                const int pos = (kk * 4 + quad) ^ (n & 7);
                bfr[nt] = *(const bf16x8*)((const char*)Bs + n * 128 + pos * 16);
            }
#pragma unroll
            for (int mt = 0; mt < 4; ++mt)
#pragma unroll
                for (int nt = 0; nt < 4; ++nt)
                    acc[mt][nt] = __builtin_amdgcn_mfma_f32_16x16x32_bf16(
                        af[mt], bfr[nt], acc[mt][nt], 0, 0, 0);
        }
    }

    // Epilogue: logits -> log_sigmoid, fused target sign (diag = +1).
    const float invTemp = 1.0f / TEMPERATURE;
    float lsum = 0.0f;
#pragma unroll
    for (int mt = 0; mt < 4; ++mt) {
#pragma unroll
        for (int nt = 0; nt < 4; ++nt) {
#pragma unroll
            for (int r = 0; r < 4; ++r) {
                const float logit = acc[mt][nt][r] * invTemp;
                const int grow = (int)rowBase + wm * 64 + mt * 16 + quad * 4 + r;
                const int gcol = (int)colBase + wn * 64 + nt * 16 + m16;
                const float x = (grow == gcol) ? (logit + MARGIN) : (MARGIN - logit);
                // log_sigmoid(x) = min(x,0) - log1p(exp(-|x|))
                const float e = __expf(-fabsf(x));
                lsum += fminf(x, 0.0f) - __logf(1.0f + e);
            }
        }
    }
#pragma unroll
    for (int off = 32; off > 0; off >>= 1) lsum += __shfl_down(lsum, off);
    if (lane == 0) wsums[wave] = lsum;
    __syncthreads();
    if (tid == 0)
        partial[(size_t)blockIdx.y * gridDim.x + blockIdx.x] =
            wsums[0] + wsums[1] + wsums[2] + wsums[3];
}

__global__ __launch_bounds__(256) void reduce_kernel(
    const float* __restrict__ partial, int nPartials, int N,
    float* __restrict__ out) {
    float s = 0.0f;
    for (int i = threadIdx.x; i < nPartials; i += 256) s += partial[i];
#pragma unroll
    for (int off = 32; off > 0; off >>= 1) s += __shfl_down(s, off);
    __shared__ float ws[4];
    const int wave = threadIdx.x >> 6;
    const int lane = threadIdx.x & 63;
    if (lane == 0) ws[wave] = s;
    __syncthreads();
    if (threadIdx.x == 0) out[0] = -(ws[0] + ws[1] + ws[2] + ws[3]) / (float)N;
}

extern "C" void kernel_launch(void* const* d_in, const int* in_sizes, int n_in,
                              void* d_out, int out_size, void* d_ws, size_t ws_size,
                              hipStream_t stream) {
    (void)n_in; (void)out_size; (void)ws_size;
    const float* s_in = (const float*)d_in[0];
    const float* t_in = (const float*)d_in[1];
    const int N = in_sizes[0] / D_DIM;  // 16384

    unsigned short* sn = (unsigned short*)d_ws;                  // N*512 bf16
    unsigned short* tn = sn + (size_t)N * D_DIM;                 // N*512 bf16
    float* partial = (float*)(tn + (size_t)N * D_DIM);           // (N/128)^2 floats

    normalize_rows_kernel<<<N, 64, 0, stream>>>(s_in, sn);
    normalize_rows_kernel<<<N, 64, 0, stream>>>(t_in, tn);

    dim3 grid(N / BN, N / BM);
    gemm_loss_kernel<<<grid, 256, 0, stream>>>(sn, tn, partial, N);

    const int nPartials = (N / BM) * (N / BN);
    reduce_kernel<<<1, 256, 0, stream>>>(partial, nPartials, N, (float*)d_out);
}

// Round 2
// 451.858 us; speedup vs baseline: 1.1519x; 1.1519x over previous
//
#include <hip/hip_runtime.h>
#include <stdint.h>

#define TEMPERATURE 0.07f
#define MARGIN 0.1f
#define D_DIM 512
#define BM 128
#define BN 256
#define BK 64

typedef __bf16 bf16x8 __attribute__((ext_vector_type(8)));
typedef float f32x4 __attribute__((ext_vector_type(4)));

__device__ __forceinline__ unsigned short f2bf(float f) {
    unsigned int u = __float_as_uint(f);
    unsigned int r = (u + 0x7fffu + ((u >> 16) & 1u)) >> 16;  // RNE
    return (unsigned short)r;
}

// softplus(x) = max(x,0) + log1p(exp(-|x|))
__device__ __forceinline__ float softplus(float x) {
    return fmaxf(x, 0.0f) + __logf(1.0f + __expf(-fabsf(x)));
}

// Direct global->LDS async copy, 16B per lane. LDS dest is wave-uniform base,
// HW adds lane*16.
__device__ __forceinline__ void async_load16(const void* gptr, const void* lptr) {
    __builtin_amdgcn_global_load_lds(
        (const __attribute__((address_space(1))) uint32_t*)(uintptr_t)gptr,
        (__attribute__((address_space(3))) uint32_t*)(uint32_t)(uintptr_t)lptr,
        16, 0, 0);
}

// One wave per row: L2-normalize 512 fp32 -> bf16 bits. Grid 2N: first N rows
// from S, next N rows from T.
__global__ __launch_bounds__(64) void normalize_rows_kernel(
    const float* __restrict__ s_in, const float* __restrict__ t_in,
    unsigned short* __restrict__ sn, unsigned short* __restrict__ tn, int N) {
    const int r = blockIdx.x;
    const float* in = (r < N) ? (s_in + (size_t)r * D_DIM)
                              : (t_in + (size_t)(r - N) * D_DIM);
    unsigned short* out = (r < N) ? (sn + (size_t)r * D_DIM)
                                  : (tn + (size_t)(r - N) * D_DIM);
    const int lane = threadIdx.x;
    const float4* in4 = (const float4*)in;
    float4 a = in4[lane];
    float4 b = in4[lane + 64];
    float ss = a.x * a.x + a.y * a.y + a.z * a.z + a.w * a.w +
               b.x * b.x + b.y * b.y + b.z * b.z + b.w * b.w;
#pragma unroll
    for (int off = 32; off > 0; off >>= 1) ss += __shfl_down(ss, off);
    ss = __shfl(ss, 0);
    const float inv = 1.0f / fmaxf(sqrtf(ss), 1e-12f);
    ushort4 oa, ob;
    oa.x = f2bf(a.x * inv); oa.y = f2bf(a.y * inv);
    oa.z = f2bf(a.z * inv); oa.w = f2bf(a.w * inv);
    ob.x = f2bf(b.x * inv); ob.y = f2bf(b.y * inv);
    ob.z = f2bf(b.z * inv); ob.w = f2bf(b.w * inv);
    ushort4* o4 = (ushort4*)out;
    o4[lane] = oa;
    o4[lane + 64] = ob;
}

// Diagonal correction: GEMM epilogue applies the off-diagonal formula
// softplus(l - margin) to ALL elements; true diagonal term is
// softplus(-l - margin). corr[i] = sp(-l_ii-m) - sp(l_ii-m).
__global__ __launch_bounds__(64) void diag_corr_kernel(
    const unsigned short* __restrict__ sn, const unsigned short* __restrict__ tn,
    float* __restrict__ corr) {
    const int row = blockIdx.x;
    const int lane = threadIdx.x;
    const bf16x8 a = *(const bf16x8*)(sn + (size_t)row * D_DIM + lane * 8);
    const bf16x8 b = *(const bf16x8*)(tn + (size_t)row * D_DIM + lane * 8);
    float dot = 0.0f;
#pragma unroll
    for (int j = 0; j < 8; ++j) dot += (float)a[j] * (float)b[j];
#pragma unroll
    for (int off = 32; off > 0; off >>= 1) dot += __shfl_down(dot, off);
    if (lane == 0) {
        const float l = dot * (1.0f / TEMPERATURE);
        corr[row] = softplus(-l - MARGIN) - softplus(l - MARGIN);
    }
}

// 128x256 tile of logits per block; 4 waves in 2x2, wave tile 64x128 (4x8 of
// 16x16x32 MFMA). Fused uniform softplus epilogue. 2 blocks/CU resident.
__global__ __launch_bounds__(256, 2) void gemm_loss_kernel(
    const unsigned short* __restrict__ S, const unsigned short* __restrict__ T,
    float* __restrict__ partial) {
    __shared__ __align__(16) unsigned short As[BM * BK];  // 16 KB
    __shared__ __align__(16) unsigned short Bs[BN * BK];  // 32 KB
    __shared__ float wsums[4];

    const int tid = threadIdx.x;
    const int wave = tid >> 6;
    const int lane = tid & 63;
    const int wm = wave >> 1;      // 0..1: 64-row half
    const int wn = wave & 1;       // 0..1: 128-col half
    const int quad = lane >> 4;
    const int m16 = lane & 15;

    // XCD super-tile swizzle. Grid 8192 = 128(tm) x 64(tn) tiles. Assumed
    // round-robin block->XCD (b&7). Super-tile = 16x4 blocks = 2048x1024
    // elements = 3 MB of S+T rows -> fits one XCD's 4 MB L2. 64 blocks per
    // super-tile == concurrent set per XCD (2 blocks/CU x 32 CU).
    const int b = blockIdx.x;
    const int xcd = b & 7;
    const int slot = b >> 3;          // 0..1023
    const int sidx = slot >> 6;       // 0..15 (sequential super-tiles per XCD)
    const int within = slot & 63;     // 0..63
    const int st = sidx * 8 + xcd;    // 0..127 super-tile id
    const int str_ = st >> 4;         // 0..7
    const int stc = st & 15;          // 0..15
    const int tm = str_ * 16 + (within >> 2);  // 0..127
    const int tn_ = stc * 4 + (within & 3);    // 0..63

    const size_t rowBase = (size_t)tm * BM;
    const size_t colBase = (size_t)tn_ * BN;

    f32x4 acc[4][8];
#pragma unroll
    for (int i = 0; i < 4; ++i)
#pragma unroll
        for (int j = 0; j < 8; ++j) acc[i][j] = (f32x4){0.f, 0.f, 0.f, 0.f};

    // Staging: chunk = 1 KB = 8 rows x 64 bf16. Lane writes LDS base+16*lane
    // (HW); we fetch global k-chunk (lane&7)^(row&7) so the XOR-swizzled
    // layout yields conflict-free ds_read_b128 on the read side.
    const int sub = lane >> 3;
    const int kch = (lane & 7) ^ sub;
    const unsigned short* Sg = S + rowBase * D_DIM;
    const unsigned short* Tg = T + colBase * D_DIM;

    for (int k0 = 0; k0 < D_DIM; k0 += BK) {
        __syncthreads();  // previous tile fully consumed
#pragma unroll
        for (int r = 0; r < 4; ++r) {  // A: 16 chunks over 4 waves
            const int c = wave * 4 + r;
            const size_t goff = (size_t)(c * 8 + sub) * D_DIM + k0 + kch * 8;
            async_load16(Sg + goff, (const char*)As + c * 1024);
        }
#pragma unroll
        for (int r = 0; r < 8; ++r) {  // B: 32 chunks over 4 waves
            const int c = wave * 8 + r;
            const size_t goff = (size_t)(c * 8 + sub) * D_DIM + k0 + kch * 8;
            async_load16(Tg + goff, (const char*)Bs + c * 1024);
        }
        __syncthreads();  // staging complete (vmcnt(0) drain)
#pragma unroll
        for (int kk = 0; kk < 2; ++kk) {
            const int pos = (kk * 4 + quad) ^ (m16 & 7);
            bf16x8 af[4], bfr[8];
#pragma unroll
            for (int mt = 0; mt < 4; ++mt) {
                const int m = wm * 64 + mt * 16 + m16;
                af[mt] = *(const bf16x8*)((const char*)As + m * 128 + pos * 16);
            }
#pragma unroll
            for (int nt = 0; nt < 8; ++nt) {
                const int n = wn * 128 + nt * 16 + m16;
                bfr[nt] = *(const bf16x8*)((const char*)Bs + n * 128 + pos * 16);
            }
#pragma unroll
            for (int mt = 0; mt < 4; ++mt)
#pragma unroll
                for (int nt = 0; nt < 8; ++nt)
                    acc[mt][nt] = __builtin_amdgcn_mfma_f32_16x16x32_bf16(
                        af[mt], bfr[nt], acc[mt][nt], 0, 0, 0);
        }
    }

    // Uniform epilogue: sum softplus(logit - margin) over all 128 elems/lane.
    // No index math; diagonal fixed up by diag_corr_kernel.
    const float invTemp = 1.0f / TEMPERATURE;
    float lsum = 0.0f;
#pragma unroll
    for (int mt = 0; mt < 4; ++mt)
#pragma unroll
        for (int nt = 0; nt < 8; ++nt)
#pragma unroll
            for (int r = 0; r < 4; ++r) {
                const float z = fmaf(acc[mt][nt][r], invTemp, -MARGIN);
                lsum += fmaxf(z, 0.0f) +
                        __logf(1.0f + __expf(-fabsf(z)));
            }
#pragma unroll
    for (int off = 32; off > 0; off >>= 1) lsum += __shfl_down(lsum, off);
    if (lane == 0) wsums[wave] = lsum;
    __syncthreads();
    if (tid == 0)
        partial[b] = wsums[0] + wsums[1] + wsums[2] + wsums[3];
}

__global__ __launch_bounds__(256) void reduce_kernel(
    const float* __restrict__ partial, int nPartials,
    const float* __restrict__ corr, int nCorr, int N,
    float* __restrict__ out) {
    float s = 0.0f;
    for (int i = threadIdx.x; i < nPartials; i += 256) s += partial[i];
    for (int i = threadIdx.x; i < nCorr; i += 256) s += corr[i];
#pragma unroll
    for (int off = 32; off > 0; off >>= 1) s += __shfl_down(s, off);
    __shared__ float ws[4];
    const int wave = threadIdx.x >> 6;
    const int lane = threadIdx.x & 63;
    if (lane == 0) ws[wave] = s;
    __syncthreads();
    if (threadIdx.x == 0) out[0] = (ws[0] + ws[1] + ws[2] + ws[3]) / (float)N;
}

extern "C" void kernel_launch(void* const* d_in, const int* in_sizes, int n_in,
                              void* d_out, int out_size, void* d_ws, size_t ws_size,
                              hipStream_t stream) {
    (void)n_in; (void)out_size; (void)ws_size;
    const float* s_in = (const float*)d_in[0];
    const float* t_in = (const float*)d_in[1];
    const int N = in_sizes[0] / D_DIM;  // 16384

    unsigned short* sn = (unsigned short*)d_ws;                  // N*512 bf16
    unsigned short* tn = sn + (size_t)N * D_DIM;                 // N*512 bf16
    float* partial = (float*)(tn + (size_t)N * D_DIM);           // 8192 floats
    const int nPartials = (N / BM) * (N / BN);
    float* corr = partial + nPartials;                           // N floats

    normalize_rows_kernel<<<2 * N, 64, 0, stream>>>(s_in, t_in, sn, tn, N);
    diag_corr_kernel<<<N, 64, 0, stream>>>(sn, tn, corr);
    gemm_loss_kernel<<<nPartials, 256, 0, stream>>>(sn, tn, partial);
    reduce_kernel<<<1, 256, 0, stream>>>(partial, nPartials, corr, N, N,
                                         (float*)d_out);
}

// Round 3
// 320.185 us; speedup vs baseline: 1.6257x; 1.4112x over previous
//
#include <hip/hip_runtime.h>
#include <stdint.h>

#define TEMPERATURE 0.07f
#define MARGIN 0.1f
#define D_DIM 512          // elements per row
#define BM 128
#define BN 256
#define BK 128             // K per MFMA step (fp8 bytes)
#define QSCALE 32.0f       // pre-quantization scale (2^5)
#define SCALE_BYTE 0x7A7A7A7A  // e8m0 2^-5 replicated

typedef int v8i32 __attribute__((ext_vector_type(8)));
typedef float f32x4 __attribute__((ext_vector_type(4)));

// softplus(x) = max(x,0) + log1p(exp(-|x|))
__device__ __forceinline__ float softplus(float x) {
    return fmaxf(x, 0.0f) + __logf(1.0f + __expf(-fabsf(x)));
}

// Direct global->LDS async copy, 16B per lane (wave-uniform LDS base).
__device__ __forceinline__ void async_load16(const void* gptr, const void* lptr) {
    __builtin_amdgcn_global_load_lds(
        (const __attribute__((address_space(1))) uint32_t*)(uintptr_t)gptr,
        (__attribute__((address_space(3))) uint32_t*)(uint32_t)(uintptr_t)lptr,
        16, 0, 0);
}

// One wave per row: L2-normalize 512 fp32, scale by 32, quantize to e4m3.
// Grid 2N: first N rows from S, next N from T.
__global__ __launch_bounds__(64) void normalize_quant_kernel(
    const float* __restrict__ s_in, const float* __restrict__ t_in,
    unsigned char* __restrict__ sq, unsigned char* __restrict__ tq, int N) {
    const int r = blockIdx.x;
    const float* in = (r < N) ? (s_in + (size_t)r * D_DIM)
                              : (t_in + (size_t)(r - N) * D_DIM);
    unsigned char* out = (r < N) ? (sq + (size_t)r * D_DIM)
                                 : (tq + (size_t)(r - N) * D_DIM);
    const int lane = threadIdx.x;
    const float4* in4 = (const float4*)in;
    float4 a = in4[lane * 2];
    float4 b = in4[lane * 2 + 1];
    float ss = a.x * a.x + a.y * a.y + a.z * a.z + a.w * a.w +
               b.x * b.x + b.y * b.y + b.z * b.z + b.w * b.w;
#pragma unroll
    for (int off = 32; off > 0; off >>= 1) ss += __shfl_down(ss, off);
    ss = __shfl(ss, 0);
    const float inv = QSCALE / fmaxf(sqrtf(ss), 1e-12f);
    int lo = 0, hi = 0;
    lo = __builtin_amdgcn_cvt_pk_fp8_f32(a.x * inv, a.y * inv, lo, false);
    lo = __builtin_amdgcn_cvt_pk_fp8_f32(a.z * inv, a.w * inv, lo, true);
    hi = __builtin_amdgcn_cvt_pk_fp8_f32(b.x * inv, b.y * inv, hi, false);
    hi = __builtin_amdgcn_cvt_pk_fp8_f32(b.z * inv, b.w * inv, hi, true);
    uint2* o2 = (uint2*)(out);
    o2[lane] = make_uint2((unsigned)lo, (unsigned)hi);
}

// Diagonal correction from exact fp32 inputs: GEMM epilogue applied the
// off-diag formula sp(l-m) to the diagonal too; corr = sp(-l-m) - sp(l-m).
__global__ __launch_bounds__(64) void diag_corr_kernel(
    const float* __restrict__ s_in, const float* __restrict__ t_in,
    float* __restrict__ corr) {
    const int row = blockIdx.x;
    const int lane = threadIdx.x;
    const float4* s4 = (const float4*)(s_in + (size_t)row * D_DIM);
    const float4* t4 = (const float4*)(t_in + (size_t)row * D_DIM);
    float ss = 0.f, tt = 0.f, st = 0.f;
#pragma unroll
    for (int h = 0; h < 2; ++h) {
        float4 a = s4[lane * 2 + h];
        float4 b = t4[lane * 2 + h];
        ss += a.x * a.x + a.y * a.y + a.z * a.z + a.w * a.w;
        tt += b.x * b.x + b.y * b.y + b.z * b.z + b.w * b.w;
        st += a.x * b.x + a.y * b.y + a.z * b.z + a.w * b.w;
    }
#pragma unroll
    for (int off = 32; off > 0; off >>= 1) {
        ss += __shfl_down(ss, off);
        tt += __shfl_down(tt, off);
        st += __shfl_down(st, off);
    }
    if (lane == 0) {
        const float l = st / (fmaxf(sqrtf(ss), 1e-12f) * fmaxf(sqrtf(tt), 1e-12f))
                        * (1.0f / TEMPERATURE);
        corr[row] = softplus(-l - MARGIN) - softplus(l - MARGIN);
    }
}

// 128x256 logits tile per block; 4 waves 2x2, wave tile 64x128 = 4x8 of
// mfma_scale_f32_16x16x128_f8f6f4 (MX fp8, uniform scale 2^-5 both sides).
__global__ __launch_bounds__(256, 2) void gemm_loss_kernel(
    const unsigned char* __restrict__ S, const unsigned char* __restrict__ T,
    float* __restrict__ partial) {
    __shared__ __align__(16) unsigned char As[BM * BK];  // 16 KB
    __shared__ __align__(16) unsigned char Bs[BN * BK];  // 32 KB
    __shared__ float wsums[4];

    const int tid = threadIdx.x;
    const int wave = tid >> 6;
    const int lane = tid & 63;
    const int wm = wave >> 1;
    const int wn = wave & 1;
    const int quad = lane >> 4;
    const int m16 = lane & 15;

    // XCD super-tile swizzle (grid 8192 = 128x64 tiles; 16x4-block super-tile
    // = 3 MB of S+T rows -> one XCD's 4 MB L2; 64 blocks = XCD concurrent set).
    const int b = blockIdx.x;
    const int xcd = b & 7;
    const int slot = b >> 3;
    const int sidx = slot >> 6;
    const int within = slot & 63;
    const int st_ = sidx * 8 + xcd;
    const int tm = (st_ >> 4) * 16 + (within >> 2);
    const int tn_ = (st_ & 15) * 4 + (within & 3);

    const size_t rowBase = (size_t)tm * BM;
    const size_t colBase = (size_t)tn_ * BN;

    f32x4 acc[4][8];
#pragma unroll
    for (int i = 0; i < 4; ++i)
#pragma unroll
        for (int j = 0; j < 8; ++j) acc[i][j] = (f32x4){0.f, 0.f, 0.f, 0.f};

    // Staging: 1 KB chunk = 8 rows x 128 B. Lane i -> LDS base+16i = row i/8,
    // 16B-position i%8. Fetch global 16B-chunk (i%8)^(i/8) so stored position
    // p of row r holds global chunk p^(r&7) -> XOR-unswizzle on read side.
    const int sub = lane >> 3;
    const int kch = (lane & 7) ^ sub;
    const unsigned char* Sg = S + rowBase * D_DIM;
    const unsigned char* Tg = T + colBase * D_DIM;

    for (int k0 = 0; k0 < D_DIM; k0 += BK) {
        __syncthreads();
#pragma unroll
        for (int r = 0; r < 4; ++r) {  // A: 16 chunks over 4 waves
            const int c = wave * 4 + r;
            const size_t goff = (size_t)(c * 8 + sub) * D_DIM + k0 + kch * 16;
            async_load16(Sg + goff, As + c * 1024);
        }
#pragma unroll
        for (int r = 0; r < 8; ++r) {  // B: 32 chunks over 4 waves
            const int c = wave * 8 + r;
            const size_t goff = (size_t)(c * 8 + sub) * D_DIM + k0 + kch * 16;
            async_load16(Tg + goff, Bs + c * 1024);
        }
        __syncthreads();

        // A fragments: lane holds A[m][k], m = wm*64+mt*16+m16,
        // k = quad*32 + 0..31 -> 16B chunks 2q, 2q+1 (XOR-unswizzled).
        v8i32 af[4];
#pragma unroll
        for (int mt = 0; mt < 4; ++mt) {
            const int m = wm * 64 + mt * 16 + m16;
            const uint4 lo = *(const uint4*)(As + m * 128 + ((2 * quad) ^ (m & 7)) * 16);
            const uint4 hi = *(const uint4*)(As + m * 128 + ((2 * quad + 1) ^ (m & 7)) * 16);
            af[mt] = (v8i32){(int)lo.x, (int)lo.y, (int)lo.z, (int)lo.w,
                             (int)hi.x, (int)hi.y, (int)hi.z, (int)hi.w};
        }
#pragma unroll
        for (int nt = 0; nt < 8; ++nt) {
            const int n = wn * 128 + nt * 16 + m16;
            const uint4 lo = *(const uint4*)(Bs + n * 128 + ((2 * quad) ^ (n & 7)) * 16);
            const uint4 hi = *(const uint4*)(Bs + n * 128 + ((2 * quad + 1) ^ (n & 7)) * 16);
            const v8i32 bf = (v8i32){(int)lo.x, (int)lo.y, (int)lo.z, (int)lo.w,
                                     (int)hi.x, (int)hi.y, (int)hi.z, (int)hi.w};
#pragma unroll
            for (int mt = 0; mt < 4; ++mt)
                acc[mt][nt] = __builtin_amdgcn_mfma_scale_f32_16x16x128_f8f6f4(
                    af[mt], bf, acc[mt][nt], 0 /*cbsz: fp8*/, 0 /*blgp: fp8*/,
                    0, SCALE_BYTE, 0, SCALE_BYTE);
        }
    }

    // Uniform epilogue: sum softplus(logit - margin) over all elems.
    const float invTemp = 1.0f / TEMPERATURE;
    float lsum = 0.0f;
#pragma unroll
    for (int mt = 0; mt < 4; ++mt)
#pragma unroll
        for (int nt = 0; nt < 8; ++nt)
#pragma unroll
            for (int r = 0; r < 4; ++r) {
                const float z = fmaf(acc[mt][nt][r], invTemp, -MARGIN);
                lsum += fmaxf(z, 0.0f) + __logf(1.0f + __expf(-fabsf(z)));
            }
#pragma unroll
    for (int off = 32; off > 0; off >>= 1) lsum += __shfl_down(lsum, off);
    if (lane == 0) wsums[wave] = lsum;
    __syncthreads();
    if (tid == 0)
        partial[b] = wsums[0] + wsums[1] + wsums[2] + wsums[3];
}

__global__ __launch_bounds__(256) void reduce_kernel(
    const float* __restrict__ partial, int nPartials,
    const float* __restrict__ corr, int nCorr, int N,
    float* __restrict__ out) {
    float s = 0.0f;
    for (int i = threadIdx.x; i < nPartials; i += 256) s += partial[i];
    for (int i = threadIdx.x; i < nCorr; i += 256) s += corr[i];
#pragma unroll
    for (int off = 32; off > 0; off >>= 1) s += __shfl_down(s, off);
    __shared__ float ws[4];
    const int wave = threadIdx.x >> 6;
    const int lane = threadIdx.x & 63;
    if (lane == 0) ws[wave] = s;
    __syncthreads();
    if (threadIdx.x == 0) out[0] = (ws[0] + ws[1] + ws[2] + ws[3]) / (float)N;
}

extern "C" void kernel_launch(void* const* d_in, const int* in_sizes, int n_in,
                              void* d_out, int out_size, void* d_ws, size_t ws_size,
                              hipStream_t stream) {
    (void)n_in; (void)out_size; (void)ws_size;
    const float* s_in = (const float*)d_in[0];
    const float* t_in = (const float*)d_in[1];
    const int N = in_sizes[0] / D_DIM;  // 16384

    unsigned char* sq = (unsigned char*)d_ws;                    // N*512 fp8
    unsigned char* tq = sq + (size_t)N * D_DIM;                  // N*512 fp8
    float* partial = (float*)(tq + (size_t)N * D_DIM);           // 8192 floats
    const int nPartials = (N / BM) * (N / BN);
    float* corr = partial + nPartials;                           // N floats

    normalize_quant_kernel<<<2 * N, 64, 0, stream>>>(s_in, t_in, sq, tq, N);
    diag_corr_kernel<<<N, 64, 0, stream>>>(s_in, t_in, corr);
    gemm_loss_kernel<<<nPartials, 256, 0, stream>>>(sq, tq, partial);
    reduce_kernel<<<1, 256, 0, stream>>>(partial, nPartials, corr, N, N,
                                         (float*)d_out);
}

// Round 4
// 305.158 us; speedup vs baseline: 1.7057x; 1.0492x over previous
//
#include <hip/hip_runtime.h>
#include <stdint.h>

#define TEMPERATURE 0.07f
#define MARGIN 0.1f
#define D_DIM 512          // elements per row
#define BM 128
#define BN 256
#define QSCALE 32.0f       // pre-quantization scale (2^5)
#define SCALE_BYTE 0x7A7A7A7A  // e8m0 2^-5 replicated (compensates QSCALE^2)

// Packed fragment-major layout (per matrix, N*512 bytes):
//   elem [row][k] -> (row>>4)*8192 + (k>>7)*2048 + ((k>>5)&3)*512
//                    + (row&15)*32 + (k&31)
// so MFMA fragment (panel p, kstep ks) for lane L is 32 contiguous bytes at
//   p*8192 + ks*2048 + L*32         (L = (k-half)*16 + row-within-panel)

typedef int v8i32 __attribute__((ext_vector_type(8)));
typedef float f32x4 __attribute__((ext_vector_type(4)));

__device__ __forceinline__ float softplus(float x) {
    return fmaxf(x, 0.0f) + __logf(1.0f + __expf(-fabsf(x)));
}

// Fused: L2-normalize row of S and T, quantize to e4m3 (x32), write packed
// fragment-major layout, and emit the diagonal correction term.
// One wave per row; 4 rows per 256-thread block.
__global__ __launch_bounds__(256) void norm_quant_pack_kernel(
    const float* __restrict__ s_in, const float* __restrict__ t_in,
    unsigned char* __restrict__ sp, unsigned char* __restrict__ tp,
    float* __restrict__ corr) {
    const int row = blockIdx.x * 4 + (threadIdx.x >> 6);
    const int lane = threadIdx.x & 63;
    const float4* s4 = (const float4*)(s_in + (size_t)row * D_DIM);
    const float4* t4 = (const float4*)(t_in + (size_t)row * D_DIM);
    float4 a0 = s4[lane * 2], a1 = s4[lane * 2 + 1];
    float4 b0 = t4[lane * 2], b1 = t4[lane * 2 + 1];
    float ss = a0.x * a0.x + a0.y * a0.y + a0.z * a0.z + a0.w * a0.w +
               a1.x * a1.x + a1.y * a1.y + a1.z * a1.z + a1.w * a1.w;
    float tt = b0.x * b0.x + b0.y * b0.y + b0.z * b0.z + b0.w * b0.w +
               b1.x * b1.x + b1.y * b1.y + b1.z * b1.z + b1.w * b1.w;
    float st = a0.x * b0.x + a0.y * b0.y + a0.z * b0.z + a0.w * b0.w +
               a1.x * b1.x + a1.y * b1.y + a1.z * b1.z + a1.w * b1.w;
#pragma unroll
    for (int off = 32; off > 0; off >>= 1) {
        ss += __shfl_down(ss, off);
        tt += __shfl_down(tt, off);
        st += __shfl_down(st, off);
    }
    ss = __shfl(ss, 0);
    tt = __shfl(tt, 0);
    const float ns = fmaxf(sqrtf(ss), 1e-12f);
    const float nt = fmaxf(sqrtf(tt), 1e-12f);
    if (lane == 0) {
        const float l = st / (ns * nt) * (1.0f / TEMPERATURE);
        corr[row] = softplus(-l - MARGIN) - softplus(l - MARGIN);
    }
    const float is = QSCALE / ns, it = QSCALE / nt;
    int s_lo = 0, s_hi = 0, t_lo = 0, t_hi = 0;
    s_lo = __builtin_amdgcn_cvt_pk_fp8_f32(a0.x * is, a0.y * is, s_lo, false);
    s_lo = __builtin_amdgcn_cvt_pk_fp8_f32(a0.z * is, a0.w * is, s_lo, true);
    s_hi = __builtin_amdgcn_cvt_pk_fp8_f32(a1.x * is, a1.y * is, s_hi, false);
    s_hi = __builtin_amdgcn_cvt_pk_fp8_f32(a1.z * is, a1.w * is, s_hi, true);
    t_lo = __builtin_amdgcn_cvt_pk_fp8_f32(b0.x * it, b0.y * it, t_lo, false);
    t_lo = __builtin_amdgcn_cvt_pk_fp8_f32(b0.z * it, b0.w * it, t_lo, true);
    t_hi = __builtin_amdgcn_cvt_pk_fp8_f32(b1.x * it, b1.y * it, t_hi, false);
    t_hi = __builtin_amdgcn_cvt_pk_fp8_f32(b1.z * it, b1.w * it, t_hi, true);
    // lane owns k = 8*lane .. 8*lane+7 (one uint2, straddles no 32B boundary)
    const size_t off = (size_t)(row >> 4) * 8192 + (lane >> 4) * 2048 +
                       ((lane >> 2) & 3) * 512 + (row & 15) * 32 + (lane & 3) * 8;
    *(uint2*)(sp + off) = make_uint2((unsigned)s_lo, (unsigned)s_hi);
    *(uint2*)(tp + off) = make_uint2((unsigned)t_lo, (unsigned)t_hi);
}

// 128x256 logits tile per block; 4 waves 2x2, wave tile 64x128 = 4x8 of
// mfma_scale_f32_16x16x128_f8f6f4. NO LDS, NO barriers in the K-loop:
// fragments are coalesced 32B-per-lane global loads from the packed layout.
__global__ __launch_bounds__(256, 2) void gemm_loss_kernel(
    const unsigned char* __restrict__ Sp, const unsigned char* __restrict__ Tp,
    float* __restrict__ partial) {
    __shared__ float wsums[4];

    const int tid = threadIdx.x;
    const int wave = tid >> 6;
    const int lane = tid & 63;
    const int wm = wave >> 1;
    const int wn = wave & 1;

    // XCD super-tile swizzle (grid 8192 = 128x64 tiles; 16x4-block super-tile
    // -> 1.5 MB of S+T panels per XCD L2; 64 blocks = XCD concurrent set).
    const int b = blockIdx.x;
    const int xcd = b & 7;
    const int slot = b >> 3;
    const int sidx = slot >> 6;
    const int within = slot & 63;
    const int st_ = sidx * 8 + xcd;
    const int tm = (st_ >> 4) * 16 + (within >> 2);   // 0..127
    const int tn_ = (st_ & 15) * 4 + (within & 3);    // 0..63

    // Fragment base addresses (k-invariant part). Panels: A = tm*8+wm*4+mt,
    // B = tn*16+wn*8+nt. Fragment = 32 B at panel*8192 + ks*2048 + lane*32.
    const unsigned char* Abase =
        Sp + (size_t)(tm * 8 + wm * 4) * 8192 + lane * 32;
    const unsigned char* Bbase =
        Tp + (size_t)(tn_ * 16 + wn * 8) * 8192 + lane * 32;

    f32x4 acc[4][8];
#pragma unroll
    for (int i = 0; i < 4; ++i)
#pragma unroll
        for (int j = 0; j < 8; ++j) acc[i][j] = (f32x4){0.f, 0.f, 0.f, 0.f};

#pragma unroll
    for (int ks = 0; ks < 4; ++ks) {
        v8i32 aF[4], bF[8];
#pragma unroll
        for (int mt = 0; mt < 4; ++mt)
            aF[mt] = *(const v8i32*)(Abase + (size_t)mt * 8192 + ks * 2048);
#pragma unroll
        for (int nt = 0; nt < 8; ++nt)
            bF[nt] = *(const v8i32*)(Bbase + (size_t)nt * 8192 + ks * 2048);
#pragma unroll
        for (int nt = 0; nt < 8; ++nt)
#pragma unroll
            for (int mt = 0; mt < 4; ++mt)
                acc[mt][nt] = __builtin_amdgcn_mfma_scale_f32_16x16x128_f8f6f4(
                    aF[mt], bF[nt], acc[mt][nt], 0 /*cbsz*/, 0 /*blgp*/,
                    0, SCALE_BYTE, 0, SCALE_BYTE);
    }

    // Uniform epilogue: sum softplus(logit - margin) over all elems (C/D
    // layout irrelevant — full reduction; diagonal fixed by corr).
    const float invTemp = 1.0f / TEMPERATURE;
    float lsum = 0.0f;
#pragma unroll
    for (int mt = 0; mt < 4; ++mt)
#pragma unroll
        for (int nt = 0; nt < 8; ++nt)
#pragma unroll
            for (int r = 0; r < 4; ++r) {
                const float z = fmaf(acc[mt][nt][r], invTemp, -MARGIN);
                lsum += fmaxf(z, 0.0f) + __logf(1.0f + __expf(-fabsf(z)));
            }
#pragma unroll
    for (int off = 32; off > 0; off >>= 1) lsum += __shfl_down(lsum, off);
    if (lane == 0) wsums[wave] = lsum;
    __syncthreads();
    if (tid == 0)
        partial[b] = wsums[0] + wsums[1] + wsums[2] + wsums[3];
}

__global__ __launch_bounds__(256) void reduce_kernel(
    const float* __restrict__ partial, int nPartials,
    const float* __restrict__ corr, int nCorr, int N,
    float* __restrict__ out) {
    float s = 0.0f;
    for (int i = threadIdx.x; i < nPartials; i += 256) s += partial[i];
    for (int i = threadIdx.x; i < nCorr; i += 256) s += corr[i];
#pragma unroll
    for (int off = 32; off > 0; off >>= 1) s += __shfl_down(s, off);
    __shared__ float ws[4];
    const int wave = threadIdx.x >> 6;
    const int lane = threadIdx.x & 63;
    if (lane == 0) ws[wave] = s;
    __syncthreads();
    if (threadIdx.x == 0) out[0] = (ws[0] + ws[1] + ws[2] + ws[3]) / (float)N;
}

extern "C" void kernel_launch(void* const* d_in, const int* in_sizes, int n_in,
                              void* d_out, int out_size, void* d_ws, size_t ws_size,
                              hipStream_t stream) {
    (void)n_in; (void)out_size; (void)ws_size;
    const float* s_in = (const float*)d_in[0];
    const float* t_in = (const float*)d_in[1];
    const int N = in_sizes[0] / D_DIM;  // 16384

    unsigned char* sp = (unsigned char*)d_ws;                    // N*512 fp8 packed
    unsigned char* tp = sp + (size_t)N * D_DIM;                  // N*512 fp8 packed
    float* partial = (float*)(tp + (size_t)N * D_DIM);           // 8192 floats
    const int nPartials = (N / BM) * (N / BN);
    float* corr = partial + nPartials;                           // N floats

    norm_quant_pack_kernel<<<N / 4, 256, 0, stream>>>(s_in, t_in, sp, tp, corr);
    gemm_loss_kernel<<<nPartials, 256, 0, stream>>>(sp, tp, partial);
    reduce_kernel<<<1, 256, 0, stream>>>(partial, nPartials, corr, N, N,
                                         (float*)d_out);
}